// Round 1
// baseline (84.393 us; speedup 1.0000x reference)
//
#include <hip/hip_runtime.h>
#include <stdint.h>

#define B_N   16384
#define F_N   512
#define NSTEP 256              // 255 real sites + identity pad at step 0
#define CHUNK 8
#define NCHUNK (NSTEP/CHUNK)

typedef float    f32x16 __attribute__((ext_vector_type(16)));
typedef short    s16x8  __attribute__((ext_vector_type(8)));
typedef int      i32x4  __attribute__((ext_vector_type(4)));
typedef unsigned u32x2  __attribute__((ext_vector_type(2)));

// ws layout (in shorts): left frags [0,262144), right frags [262144,524288),
// M frag [524288,525312), c0 (float) at short offset 525312.
#define WS_SIDE_STRIDE 262144
#define WS_MFRAG_S     524288
#define WS_C0_S        525312
#define WS_BYTES_NEEDED (525312*2 + 4)

// pack {bf16_trunc(f0) in lo16, bf16_trunc(f1) in hi16}
static __device__ __forceinline__ void split_pack8(const float* f, unsigned* ph, unsigned* pl) {
#pragma unroll
  for (int j = 0; j < 4; ++j) {
    float f0 = f[2*j], f1 = f[2*j+1];
    unsigned u0 = __float_as_uint(f0), u1 = __float_as_uint(f1);
    ph[j] = __builtin_amdgcn_perm(u1, u0, 0x07060302u);            // hi parts
    float l0 = f0 - __uint_as_float(u0 & 0xffff0000u);
    float l1 = f1 - __uint_as_float(u1 & 0xffff0000u);
    pl[j] = __builtin_amdgcn_perm(__float_as_uint(l1), __float_as_uint(l0), 0x07060302u);
  }
}

// exchange: new_a = {a(lo lanes), b from partner(hi lanes)}, new_b = {a from partner(lo), b(hi)}
static __device__ __forceinline__ void half_swap(unsigned &a, unsigned &b) {
#if __has_builtin(__builtin_amdgcn_permlane32_swap)
  u32x2 r = __builtin_amdgcn_permlane32_swap(a, b, false, false);
  a = (unsigned)r.x; b = (unsigned)r.y;
#else
  unsigned oa = (unsigned)__shfl_xor((int)a, 32, 64);
  unsigned ob = (unsigned)__shfl_xor((int)b, 32, 64);
  bool hi = (threadIdx.x & 32) != 0;
  unsigned na = hi ? ob : a;
  unsigned nb = hi ? b  : oa;
  a = na; b = nb;
#endif
}

static __device__ __forceinline__ s16x8 as_s16x8(const unsigned* p) {
  i32x4 v; v.x = (int)p[0]; v.y = (int)p[1]; v.z = (int)p[2]; v.w = (int)p[3];
  return __builtin_bit_cast(s16x8, v);
}

// ---------------- prep: build MFMA A-operand fragments (hi/lo bf16 split) ----------------
// A-layout assumed: lane l holds A[row = l&31][k = 8*(l>>5)+i], i=0..7, pairs packed lo16-first.
// Left  (site s>=1): A[m][d] = W_left[s-1][d][m>>4][m&15]   (v_new = [W0^T;W1^T] v)
// Right (site s>=1): A[m][e] = W_right[255-s][m&15][m>>4][e] (u_new = [W0;W1] u)
// site 0: identity pad (D0 = v, D1 = 0).
__global__ __launch_bounds__(256) void mps_prep(
    const float* __restrict__ W0, const float* __restrict__ W_left,
    const float* __restrict__ W_out, const float* __restrict__ W_right,
    const float* __restrict__ WN, const float* __restrict__ d1_w,
    const float* __restrict__ d1_b, const float* __restrict__ d2_w,
    const float* __restrict__ d2_b, unsigned short* __restrict__ ws)
{
  int bid = blockIdx.x;
  if (bid < 128) {
    int tid  = bid * 256 + threadIdx.x;     // 32768 threads = 2 sides * 256 sites * 64 lanes
    int side = tid >> 14;
    int rem  = tid & 16383;
    int site = rem >> 6;
    int lane = rem & 63;
    int m  = lane & 31;
    int kb = (lane >> 5) * 8;
    s16x8 hv, lv;
#pragma unroll
    for (int i = 0; i < 8; ++i) {
      int k = kb + i;
      float w;
      if (site == 0)       w = (m < 16 && k == m) ? 1.0f : 0.0f;
      else if (side == 0)  w = W_left [(site-1)*512 + k*32      + (m>>4)*16 + (m&15)];
      else                 w = W_right[(255-site)*512 + (m&15)*32 + (m>>4)*16 + k];
      unsigned u = __float_as_uint(w);
      unsigned short h = (unsigned short)(u >> 16);
      float lo = w - __uint_as_float((unsigned)h << 16);
      unsigned short l = (unsigned short)(__float_as_uint(lo) >> 16);
      hv[i] = (short)h; lv[i] = (short)l;
    }
    size_t base = (size_t)side * WS_SIDE_STRIDE + (size_t)site * 1024 + (size_t)lane * 8;
    *reinterpret_cast<s16x8*>(ws + base)       = hv;   // term 0 (hi)
    *reinterpret_cast<s16x8*>(ws + base + 512) = lv;   // term 1 (lo)
  } else {
    // M[d][e] = sum_o wef[o] * W_out[d][o][e],  wef[o] = sum_h d2_w[h]*d1_w[h][o]
    __shared__ float Msh[256];
    int t = threadIdx.x;
    int d = t >> 4, e = t & 15;
    float acc = 0.f;
#pragma unroll
    for (int o = 0; o < 8; ++o) {
      float wef = 0.f;
      for (int hh = 0; hh < 24; ++hh) wef += d2_w[hh] * d1_w[hh*8 + o];
      acc += wef * W_out[d*128 + o*16 + e];
    }
    Msh[d*16 + e] = acc;
    __syncthreads();
    if (t < 128) {
      int term = t >> 6, lane = t & 63;
      int m = lane & 31, kb = (lane >> 5) * 8;
      s16x8 v8;
#pragma unroll
      for (int i = 0; i < 8; ++i) {
        float w = (m < 16) ? Msh[(kb+i)*16 + m] : 0.f;   // A[m][k=d] = M[d][m]
        unsigned u = __float_as_uint(w);
        unsigned short hh = (unsigned short)(u >> 16);
        if (term) {
          float lo = w - __uint_as_float((unsigned)hh << 16);
          hh = (unsigned short)(__float_as_uint(lo) >> 16);
        }
        v8[i] = (short)hh;
      }
      *reinterpret_cast<s16x8*>(ws + WS_MFRAG_S + term*512 + lane*8) = v8;
    }
    if (t == 0) {
      float c0 = d2_b[0];
      for (int hh = 0; hh < 24; ++hh) c0 += d2_w[hh] * d1_b[hh];
      *reinterpret_cast<float*>(ws + WS_C0_S) = c0;
    }
  }
}

// ---------------- main: 4 waves/block: {left,left,right,right} x 32 samples each ----------------
__global__ __launch_bounds__(256) void mps_main(
    const float* __restrict__ x, const float* __restrict__ W0,
    const float* __restrict__ WN, const unsigned short* __restrict__ ws,
    float* __restrict__ out)
{
  __shared__ __align__(16) unsigned short sbuf[2][2][CHUNK][2][64][8]; // [side][dbuf][site][term][lane][8]
  __shared__ float u_lds[2][64][8];

  const int tidx = threadIdx.x;
  const int wave = tidx >> 6;
  const int lane = tidx & 63;
  const int side = wave >> 1;        // 0 = left chain, 1 = right chain
  const int q    = wave & 1;         // sample-group within block
  const int col  = lane & 31;
  const int h    = lane >> 5;
  const int b    = blockIdx.x * 64 + q * 32 + col;
  const float* xrow = x + (size_t)b * F_N;
  const unsigned short* frag = ws + (size_t)side * WS_SIDE_STRIDE;

  // init vector: v0[d] = W0[0][d] + x[0]*W0[1][d] ; u0[e] = WN[e][0] + x[511]*WN[e][1]
  float f0[8];
  {
    float xi = side ? xrow[F_N-1] : xrow[0];
#pragma unroll
    for (int i = 0; i < 8; ++i) {
      int idx = h*8 + i;                               // this lane's k-range (B-operand)
      float a0 = side ? WN[idx*2]   : W0[idx];
      float a1 = side ? WN[idx*2+1] : W0[16+idx];
      f0[i] = fmaf(xi, a1, a0);
    }
  }
  unsigned vhi[4], vlo[4];
  split_pack8(f0, vhi, vlo);                            // already per-lane B-layout: no swap

  f32x16 Dz;
#pragma unroll
  for (int i = 0; i < 16; ++i) Dz[i] = 0.f;

  auto stage = [&](int chunk, int db) {
    const unsigned short* gs = frag + (size_t)chunk * (CHUNK*1024) + (size_t)lane * 8;
#pragma unroll
    for (int s2 = 0; s2 < 4; ++s2) {
      int sc = q*4 + s2;
#pragma unroll
      for (int term = 0; term < 2; ++term) {
        __builtin_amdgcn_global_load_lds(
          (const __attribute__((address_space(1))) void*)(gs + sc*1024 + term*512),
          (__attribute__((address_space(3))) void*)(&sbuf[side][db][sc][term][0][0]),
          16, 0, 0);
      }
    }
  };

  stage(0, 0);
  asm volatile("s_waitcnt vmcnt(0)" ::: "memory");
  __syncthreads();

  float4 xb;
  float dcomb[8];
#pragma unroll 1
  for (int c = 0; c < NCHUNK; ++c) {
    if (c + 1 < NCHUNK) stage(c + 1, (c + 1) & 1);
    const unsigned short* lb = &sbuf[side][c & 1][0][0][0][0];
#pragma unroll
    for (int sc = 0; sc < CHUNK; ++sc) {
      int step = c*CHUNK + sc;
      if ((sc & 3) == 0) {
        int basei = side ? (508 - step) : step;        // aligned float4
        xb = *reinterpret_cast<const float4*>(xrow + basei);
      }
      int cmp = side ? (3 - (sc & 3)) : (sc & 3);
      float xv = (cmp == 0) ? xb.x : (cmp == 1) ? xb.y : (cmp == 2) ? xb.z : xb.w;

      s16x8 ahi = *reinterpret_cast<const s16x8*>(lb + sc*1024 + 0*512 + lane*8);
      s16x8 alo = *reinterpret_cast<const s16x8*>(lb + sc*1024 + 1*512 + lane*8);
      s16x8 vh = as_s16x8(vhi);
      s16x8 vl = as_s16x8(vlo);

      f32x16 D = __builtin_amdgcn_mfma_f32_32x32x16_bf16(ahi, vh, Dz, 0, 0, 0);
      D = __builtin_amdgcn_mfma_f32_32x32x16_bf16(ahi, vl, D, 0, 0, 0);
      D = __builtin_amdgcn_mfma_f32_32x32x16_bf16(alo, vh, D, 0, 0, 0);

      // v_new = D0 + x * D1  (row r+16 lives in reg r+8)
#pragma unroll
      for (int r = 0; r < 8; ++r) dcomb[r] = fmaf(xv, D[r+8], D[r]);

      // split to bf16 hi/lo, pack pairs, exchange halves into B-operand layout
      unsigned P[4], Q[4];
      split_pack8(dcomb, P, Q);
      half_swap(P[0], P[2]);  half_swap(P[1], P[3]);
      half_swap(Q[0], Q[2]);  half_swap(Q[1], Q[3]);
      vhi[0]=P[0]; vhi[1]=P[1]; vhi[2]=P[2]; vhi[3]=P[3];
      vlo[0]=Q[0]; vlo[1]=Q[1]; vlo[2]=Q[2]; vlo[3]=Q[3];
    }
    asm volatile("s_waitcnt vmcnt(0)" ::: "memory");
    __syncthreads();
  }

  // epilogue: y[b] = c0 + sum_e z[e,b] * u[e,b],  z = M^T v (stacked-M MFMA, rows 16..31 are 0)
  if (side == 1) {
#pragma unroll
    for (int r = 0; r < 8; ++r) u_lds[q][lane][r] = dcomb[r];   // final u, f32 D-layout
  }
  __syncthreads();
  if (side == 0) {
    s16x8 mhi = *reinterpret_cast<const s16x8*>(ws + WS_MFRAG_S + 0*512 + lane*8);
    s16x8 mlo = *reinterpret_cast<const s16x8*>(ws + WS_MFRAG_S + 1*512 + lane*8);
    s16x8 vh = as_s16x8(vhi);
    s16x8 vl = as_s16x8(vlo);
    f32x16 Z = __builtin_amdgcn_mfma_f32_32x32x16_bf16(mhi, vh, Dz, 0, 0, 0);
    Z = __builtin_amdgcn_mfma_f32_32x32x16_bf16(mhi, vl, Z, 0, 0, 0);
    Z = __builtin_amdgcn_mfma_f32_32x32x16_bf16(mlo, vh, Z, 0, 0, 0);
    float part = 0.f;
#pragma unroll
    for (int r = 0; r < 8; ++r) part = fmaf(Z[r], u_lds[q][lane][r], part);
    float other = __shfl_xor(part, 32, 64);
    float c0 = *reinterpret_cast<const float*>(ws + WS_C0_S);
    if (h == 0) out[b] = part + other + c0;
  }
}

extern "C" void kernel_launch(void* const* d_in, const int* in_sizes, int n_in,
                              void* d_out, int out_size, void* d_ws, size_t ws_size,
                              hipStream_t stream)
{
  const float* x       = (const float*)d_in[0];
  const float* W0      = (const float*)d_in[1];
  const float* W_left  = (const float*)d_in[2];
  const float* W_out   = (const float*)d_in[3];
  const float* W_right = (const float*)d_in[4];
  const float* WN      = (const float*)d_in[5];
  const float* d1_w    = (const float*)d_in[6];
  const float* d1_b    = (const float*)d_in[7];
  const float* d2_w    = (const float*)d_in[8];
  const float* d2_b    = (const float*)d_in[9];
  unsigned short* ws   = (unsigned short*)d_ws;
  float* out           = (float*)d_out;

  if (ws_size < (size_t)WS_BYTES_NEEDED) return;

  hipLaunchKernelGGL(mps_prep, dim3(129), dim3(256), 0, stream,
                     W0, W_left, W_out, W_right, WN, d1_w, d1_b, d2_w, d2_b, ws);
  hipLaunchKernelGGL(mps_main, dim3(B_N/64), dim3(256), 0, stream,
                     x, W0, WN, ws, out);
}

// Round 2
// 83.702 us; speedup vs baseline: 1.0082x; 1.0082x over previous
//
#include <hip/hip_runtime.h>
#include <stdint.h>

#define B_N   16384
#define F_N   512
#define NSTEP 256              // 255 real sites + identity pad at step 0
#define CHUNK 8
#define NCHUNK (NSTEP/CHUNK)

typedef float    f32x4  __attribute__((ext_vector_type(4)));
typedef short    s16x8  __attribute__((ext_vector_type(8)));
typedef int      i32x4  __attribute__((ext_vector_type(4)));
typedef unsigned u32x2  __attribute__((ext_vector_type(2)));

// ws layout (in shorts): left frags [0,262144), right frags [262144,524288),
// then M (256 f32) at short offset 524288, c0 (f32) at short offset 524800.
#define WS_SIDE_STRIDE 262144
#define WS_M_S         524288            // float index 262144
#define WS_C0_S        524800            // float index 262400
#define WS_BYTES_NEEDED ((WS_C0_S + 2) * 2)

// pack 4 floats -> 2 packed-bf16 hi words + 2 packed-bf16 lo words (trunc split)
static __device__ __forceinline__ void split4(const float* f, unsigned* ph, unsigned* pl) {
#pragma unroll
  for (int j = 0; j < 2; ++j) {
    float f0 = f[2*j], f1 = f[2*j+1];
    unsigned u0 = __float_as_uint(f0), u1 = __float_as_uint(f1);
    ph[j] = __builtin_amdgcn_perm(u1, u0, 0x07060302u);            // hi bf16 pair
    float l0 = f0 - __uint_as_float(u0 & 0xffff0000u);
    float l1 = f1 - __uint_as_float(u1 & 0xffff0000u);
    pl[j] = __builtin_amdgcn_perm(__float_as_uint(l1), __float_as_uint(l0), 0x07060302u);
  }
}

// 32-lane half swap: lo lanes: a'=a, b'=a(from l+32); hi lanes: a'=b(from l-32), b'=b
static __device__ __forceinline__ void half_swap32(unsigned &a, unsigned &b) {
#if __has_builtin(__builtin_amdgcn_permlane32_swap)
  u32x2 r = __builtin_amdgcn_permlane32_swap(a, b, false, false);
  a = (unsigned)r.x; b = (unsigned)r.y;
#else
  unsigned oa = (unsigned)__shfl_xor((int)a, 32, 64);
  unsigned ob = (unsigned)__shfl_xor((int)b, 32, 64);
  bool hi = (threadIdx.x & 32) != 0;
  unsigned na = hi ? ob : a;
  unsigned nb = hi ? b  : oa;
  a = na; b = nb;
#endif
}

// 16-lane-group swap: pairs (g0,g1) and (g2,g3); even group: a'=a, b'=a(from l+16);
// odd group: a'=b(from l-16), b'=b
static __device__ __forceinline__ void half_swap16(unsigned &a, unsigned &b) {
#if __has_builtin(__builtin_amdgcn_permlane16_swap)
  u32x2 r = __builtin_amdgcn_permlane16_swap(a, b, false, false);
  a = (unsigned)r.x; b = (unsigned)r.y;
#else
  unsigned oa = (unsigned)__shfl_xor((int)a, 16, 64);
  unsigned ob = (unsigned)__shfl_xor((int)b, 16, 64);
  bool odd = (threadIdx.x & 16) != 0;
  unsigned na = odd ? ob : a;
  unsigned nb = odd ? b  : oa;
  a = na; b = nb;
#endif
}

static __device__ __forceinline__ s16x8 as_s16x8(const unsigned* p) {
  i32x4 v; v.x = (int)p[0]; v.y = (int)p[1]; v.z = (int)p[2]; v.w = (int)p[3];
  return __builtin_bit_cast(s16x8, v);
}

// ---------------- prep: build 16x16x32 MFMA A-operand fragments (hi/lo bf16 split) ----
// A-layout: lane l holds A[row = l&15][k = 8*(l>>4)+i], i=0..7, pairs packed lo16-first.
// Left  (site s>=1): A[e][k] = W_left[s-1][k&15][k>>4][e]   (v_new = [W0^T;W1^T]_K vv)
// Right (site s>=1): A[d][k] = W_right[255-s][d][k>>4][k&15] (u_new = [W0;W1]_K vv)
// site 0: identity pad: A=[I;0] -> v_new = v.
__global__ __launch_bounds__(256) void mps_prep(
    const float* __restrict__ W0, const float* __restrict__ W_left,
    const float* __restrict__ W_out, const float* __restrict__ W_right,
    const float* __restrict__ WN, const float* __restrict__ d1_w,
    const float* __restrict__ d1_b, const float* __restrict__ d2_w,
    const float* __restrict__ d2_b, unsigned short* __restrict__ ws)
{
  int bid = blockIdx.x;
  if (bid < 128) {
    int tid  = bid * 256 + threadIdx.x;     // 32768 = 2 sides * 256 sites * 64 lanes
    int side = tid >> 14;
    int rem  = tid & 16383;
    int site = rem >> 6;
    int lane = rem & 63;
    int m  = lane & 15;
    int kb = (lane >> 4) * 8;
    s16x8 hv, lv;
#pragma unroll
    for (int i = 0; i < 8; ++i) {
      int k = kb + i;
      float w;
      if (site == 0)       w = (k == m) ? 1.0f : 0.0f;
      else if (side == 0)  w = W_left [(site-1)*512 + (k&15)*32 + (k>>4)*16 + m];
      else                 w = W_right[(255-site)*512 + m*32 + (k>>4)*16 + (k&15)];
      unsigned u = __float_as_uint(w);
      unsigned short h = (unsigned short)(u >> 16);
      float lo = w - __uint_as_float((unsigned)h << 16);
      unsigned short l = (unsigned short)(__float_as_uint(lo) >> 16);
      hv[i] = (short)h; lv[i] = (short)l;
    }
    size_t base = (size_t)side * WS_SIDE_STRIDE + (size_t)site * 1024 + (size_t)lane * 8;
    *reinterpret_cast<s16x8*>(ws + base)       = hv;   // term 0 (hi)
    *reinterpret_cast<s16x8*>(ws + base + 512) = lv;   // term 1 (lo)
  } else {
    // M[d][e] = sum_o wef[o] * W_out[d][o][e],  wef[o] = sum_h d2_w[h]*d1_w[h][o]
    int t = threadIdx.x;
    int d = t >> 4, e = t & 15;
    float acc = 0.f;
#pragma unroll
    for (int o = 0; o < 8; ++o) {
      float wef = 0.f;
      for (int hh = 0; hh < 24; ++hh) wef += d2_w[hh] * d1_w[hh*8 + o];
      acc += wef * W_out[d*128 + o*16 + e];
    }
    float* wf = reinterpret_cast<float*>(ws);
    wf[262144 + t] = acc;
    if (t == 0) {
      float c0 = d2_b[0];
      for (int hh = 0; hh < 24; ++hh) c0 += d2_w[hh] * d1_b[hh];
      wf[262400] = c0;
    }
  }
}

// ---------------- main: 4 waves/block {L,L,R,R}, 16 samples per wave, 512 blocks ------
__global__ __launch_bounds__(256) void mps_main(
    const float* __restrict__ x, const float* __restrict__ W0,
    const float* __restrict__ WN, const unsigned short* __restrict__ ws,
    float* __restrict__ out)
{
  __shared__ __align__(16) unsigned short sbuf[2][2][CHUNK][2][64][8]; // [side][dbuf][site][term][lane][8]
  __shared__ float fin[2][32][16];                                     // [side][sample][row]

  const int tidx = threadIdx.x;
  const int wave = tidx >> 6;
  const int lane = tidx & 63;
  const int side = wave >> 1;        // 0 = left chain, 1 = right chain
  const int q    = wave & 1;         // 16-sample group within block
  const int col  = lane & 15;        // sample column
  const int g    = lane >> 4;        // lane group: D rows 4g..4g+3
  const int b    = blockIdx.x * 32 + q * 16 + col;
  const float* xrow = x + (size_t)b * F_N;
  const unsigned short* frag = ws + (size_t)side * WS_SIDE_STRIDE;

  // init state (f32, D-layout): st[r] = v0[4g+r] / u0[4g+r]
  float st[4];
  {
    float xi = side ? xrow[F_N-1] : xrow[0];
#pragma unroll
    for (int r = 0; r < 4; ++r) {
      int row = g*4 + r;
      float a0 = side ? WN[row*2]   : W0[row];
      float a1 = side ? WN[row*2+1] : W0[16+row];
      st[r] = fmaf(xi, a1, a0);
    }
  }

  f32x4 Dz = {0.f, 0.f, 0.f, 0.f};

  auto stage = [&](int chunk, int db) {
    const unsigned short* gs = frag + (size_t)chunk * (CHUNK*1024) + (size_t)lane * 8;
#pragma unroll
    for (int s2 = 0; s2 < 4; ++s2) {
      int sc = q*4 + s2;
#pragma unroll
      for (int term = 0; term < 2; ++term) {
        __builtin_amdgcn_global_load_lds(
          (const __attribute__((address_space(1))) void*)(gs + sc*1024 + term*512),
          (__attribute__((address_space(3))) void*)(&sbuf[side][db][sc][term][0][0]),
          16, 0, 0);
      }
    }
  };

  stage(0, 0);
  asm volatile("s_waitcnt vmcnt(0)" ::: "memory");
  __syncthreads();

  float4 xb;
#pragma unroll 1
  for (int c = 0; c < NCHUNK; ++c) {
    if (c + 1 < NCHUNK) stage(c + 1, (c + 1) & 1);
    const unsigned short* lb = &sbuf[side][c & 1][0][0][0][0];
#pragma unroll
    for (int sc = 0; sc < CHUNK; ++sc) {
      int step = c*CHUNK + sc;
      if ((sc & 3) == 0) {
        int basei = side ? (508 - step) : step;        // aligned float4
        xb = *reinterpret_cast<const float4*>(xrow + basei);
      }
      int cmp = side ? (3 - (sc & 3)) : (sc & 3);
      float xv = (cmp == 0) ? xb.x : (cmp == 1) ? xb.y : (cmp == 2) ? xb.z : xb.w;

      // build vv = [v ; x*v] in bf16 hi/lo, B-operand layout:
      // group g' holds k=8g'..8g'+7; g0<-rows0-7(P), g1<-rows8-15(P), g2<-x*rows0-7, g3<-x*rows8-15
      float xs4[4];
#pragma unroll
      for (int r = 0; r < 4; ++r) xs4[r] = xv * st[r];
      unsigned Ph[2], Pl[2], XPh[2], XPl[2];
      split4(st,  Ph, Pl);
      split4(xs4, XPh, XPl);
      half_swap32(Ph[0], XPh[0]);  half_swap32(Ph[1], XPh[1]);
      half_swap16(Ph[0], XPh[0]);  half_swap16(Ph[1], XPh[1]);
      half_swap32(Pl[0], XPl[0]);  half_swap32(Pl[1], XPl[1]);
      half_swap16(Pl[0], XPl[0]);  half_swap16(Pl[1], XPl[1]);
      unsigned bh[4] = {Ph[0], Ph[1], XPh[0], XPh[1]};
      unsigned blo[4] = {Pl[0], Pl[1], XPl[0], XPl[1]};
      s16x8 vh = as_s16x8(bh);
      s16x8 vl = as_s16x8(blo);

      s16x8 ahi = *reinterpret_cast<const s16x8*>(lb + sc*1024 + 0*512 + lane*8);
      s16x8 alo = *reinterpret_cast<const s16x8*>(lb + sc*1024 + 1*512 + lane*8);

      f32x4 D = __builtin_amdgcn_mfma_f32_16x16x32_bf16(ahi, vh, Dz, 0, 0, 0);
      D = __builtin_amdgcn_mfma_f32_16x16x32_bf16(ahi, vl, D, 0, 0, 0);
      D = __builtin_amdgcn_mfma_f32_16x16x32_bf16(alo, vh, D, 0, 0, 0);
#pragma unroll
      for (int r = 0; r < 4; ++r) st[r] = D[r];
    }
    asm volatile("s_waitcnt vmcnt(0)" ::: "memory");
    __syncthreads();
  }

  // write final states, then per-sample head: y = c0 + v^T M u
#pragma unroll
  for (int r = 0; r < 4; ++r) fin[side][q*16 + col][g*4 + r] = st[r];
  __syncthreads();

  {
    int s = tidx >> 3, j = tidx & 7;                   // 32 samples x 8 threads
    const float* Mf = reinterpret_cast<const float*>(ws) + 262144;
    float c0 = reinterpret_cast<const float*>(ws)[262400];
    float acc = 0.f;
#pragma unroll
    for (int dd = 0; dd < 2; ++dd) {
      int d = j*2 + dd;
      float zd = 0.f;
#pragma unroll
      for (int e = 0; e < 16; ++e) zd = fmaf(Mf[d*16 + e], fin[1][s][e], zd);
      acc = fmaf(fin[0][s][d], zd, acc);
    }
    acc += __shfl_xor(acc, 1, 64);
    acc += __shfl_xor(acc, 2, 64);
    acc += __shfl_xor(acc, 4, 64);
    if (j == 0) out[blockIdx.x*32 + s] = acc + c0;
  }
}

extern "C" void kernel_launch(void* const* d_in, const int* in_sizes, int n_in,
                              void* d_out, int out_size, void* d_ws, size_t ws_size,
                              hipStream_t stream)
{
  const float* x       = (const float*)d_in[0];
  const float* W0      = (const float*)d_in[1];
  const float* W_left  = (const float*)d_in[2];
  const float* W_out   = (const float*)d_in[3];
  const float* W_right = (const float*)d_in[4];
  const float* WN      = (const float*)d_in[5];
  const float* d1_w    = (const float*)d_in[6];
  const float* d1_b    = (const float*)d_in[7];
  const float* d2_w    = (const float*)d_in[8];
  const float* d2_b    = (const float*)d_in[9];
  unsigned short* ws   = (unsigned short*)d_ws;
  float* out           = (float*)d_out;

  if (ws_size < (size_t)WS_BYTES_NEEDED) return;

  hipLaunchKernelGGL(mps_prep, dim3(129), dim3(256), 0, stream,
                     W0, W_left, W_out, W_right, WN, d1_w, d1_b, d2_w, d2_b, ws);
  hipLaunchKernelGGL(mps_main, dim3(B_N/32), dim3(256), 0, stream,
                     x, W0, WN, ws, out);
}

// Round 3
// 77.073 us; speedup vs baseline: 1.0950x; 1.0860x over previous
//
#include <hip/hip_runtime.h>
#include <stdint.h>

#define B_N    16384
#define F_N    512
#define NPAIR  128            // 256 steps (1 pad + 255 sites) fused into 128 pairs per side
#define CHUNKP 4              // pairs per staged chunk
#define NCHUNKC (NPAIR/CHUNKP)

typedef float    f32x16 __attribute__((ext_vector_type(16)));
typedef short    s16x8  __attribute__((ext_vector_type(8)));
typedef int      i32x4  __attribute__((ext_vector_type(4)));
typedef unsigned u32x2  __attribute__((ext_vector_type(2)));

// ws layout (shorts): left pair-frags [0,262144), right [262144,524288),
// M (256 f32) at short 524288, c0 at short 524800.
// per pair-side: 2048 shorts = [A1hi(512)|A1lo(512)|A2hi(512)|A2lo(512)]
#define WS_SIDE_STRIDE 262144
#define WS_BYTES_NEEDED ((524800 + 2) * 2)

static __device__ __forceinline__ void split_pack8(const float* f, unsigned* ph, unsigned* pl) {
#pragma unroll
  for (int j = 0; j < 4; ++j) {
    float f0 = f[2*j], f1 = f[2*j+1];
    unsigned u0 = __float_as_uint(f0), u1 = __float_as_uint(f1);
    ph[j] = __builtin_amdgcn_perm(u1, u0, 0x07060302u);
    float l0 = f0 - __uint_as_float(u0 & 0xffff0000u);
    float l1 = f1 - __uint_as_float(u1 & 0xffff0000u);
    pl[j] = __builtin_amdgcn_perm(__float_as_uint(l1), __float_as_uint(l0), 0x07060302u);
  }
}

static __device__ __forceinline__ void half_swap32(unsigned &a, unsigned &b) {
#if __has_builtin(__builtin_amdgcn_permlane32_swap)
  u32x2 r = __builtin_amdgcn_permlane32_swap(a, b, false, false);
  a = (unsigned)r.x; b = (unsigned)r.y;
#else
  unsigned oa = (unsigned)__shfl_xor((int)a, 32, 64);
  unsigned ob = (unsigned)__shfl_xor((int)b, 32, 64);
  bool hi = (threadIdx.x & 32) != 0;
  unsigned na = hi ? ob : a;
  unsigned nb = hi ? b  : oa;
  a = na; b = nb;
#endif
}

static __device__ __forceinline__ s16x8 as_s16x8(const unsigned* p) {
  i32x4 v; v.x = (int)p[0]; v.y = (int)p[1]; v.z = (int)p[2]; v.w = (int)p[3];
  return __builtin_bit_cast(s16x8, v);
}

// ---------------- prep: fuse site pairs into 4 product matrices, emit MFMA A-frags ----
// Left pair p: sites a=2p (pad if p==0), b=2p+1 (W_left[site-1]).
//   v'' = [P00 + xa P10 + xb P01 + xa xb P11]^T v, Pij[d][m] products of W{i}a,W{j}b.
//   A1 = [P00^T ; P10^T] (M-stacked 32x16), A2 = [P01^T ; P11^T].
// Right pair p: steps a=2p (pad if p==0, tensor 255-2p), b=2p+1 (tensor 254-2p).
//   u'' = [R00 + xa R10 + xb R01 + xa xb R11] u, A1=[R00;R10], A2=[R01;R11] (no transpose).
// A-frag layout (32x32x16): lane l holds A[m=l&31][k=8*(l>>5)+i], i=0..7.
__global__ __launch_bounds__(256) void mps_prep(
    const float* __restrict__ W0, const float* __restrict__ W_left,
    const float* __restrict__ W_out, const float* __restrict__ W_right,
    const float* __restrict__ WN, const float* __restrict__ d1_w,
    const float* __restrict__ d1_b, const float* __restrict__ d2_w,
    const float* __restrict__ d2_b, unsigned short* __restrict__ ws)
{
  int bid = blockIdx.x;
  if (bid < 256) {
    int side = bid >> 7;
    int pair = bid & 127;
    __shared__ float Wa[512];    // [d*32 + p*16 + m]
    __shared__ float Wb[512];
    __shared__ float Af[1024];   // A1[32][16] | A2[32][16]
    int t = threadIdx.x;
    bool pad_a = (pair == 0);
    const float* base_a = side ? (W_right + (size_t)(255 - 2*pair) * 512)
                               : (W_left  + (size_t)(2*pair - 1) * 512);
    const float* base_b = side ? (W_right + (size_t)(254 - 2*pair) * 512)
                               : (W_left  + (size_t)(2*pair) * 512);
#pragma unroll
    for (int e = t; e < 512; e += 256) {
      float va;
      if (pad_a) { int d = e >> 5, p = (e >> 4) & 1, m = e & 15; va = (p == 0 && d == m) ? 1.f : 0.f; }
      else va = base_a[e];
      Wa[e] = va;
      Wb[e] = base_b[e];
    }
    __syncthreads();
#pragma unroll
    for (int ei = t; ei < 1024; ei += 256) {
      int amat = ei >> 9;          // 0: A1, 1: A2 (selects phys idx of site b)
      int rem  = ei & 511;
      int m32  = rem >> 4;
      int k    = rem & 15;
      int pa   = m32 >> 4;         // phys idx of site a (row block)
      int m    = m32 & 15;
      float acc = 0.f;
      if (side == 0) {
#pragma unroll
        for (int j = 0; j < 16; ++j) acc += Wa[k*32 + pa*16 + j] * Wb[j*32 + amat*16 + m];
      } else {
#pragma unroll
        for (int j = 0; j < 16; ++j) acc += Wb[m*32 + amat*16 + j] * Wa[j*32 + pa*16 + k];
      }
      Af[ei] = acc;
    }
    __syncthreads();
    {
      int f = t >> 6, l = t & 63;          // f: 0=A1hi 1=A1lo 2=A2hi 3=A2lo
      int amat = f >> 1, lo = f & 1;
      int m32 = l & 31, kb = (l >> 5) * 8;
      s16x8 v8;
#pragma unroll
      for (int i = 0; i < 8; ++i) {
        float w = Af[amat*512 + m32*16 + kb + i];
        unsigned u = __float_as_uint(w);
        unsigned short h = (unsigned short)(u >> 16);
        if (lo) {
          float rl = w - __uint_as_float((unsigned)h << 16);
          h = (unsigned short)(__float_as_uint(rl) >> 16);
        }
        v8[i] = (short)h;
      }
      *reinterpret_cast<s16x8*>(ws + (size_t)side * WS_SIDE_STRIDE
                                   + (size_t)pair * 2048 + f * 512 + l * 8) = v8;
    }
  } else {
    // M[d][e] = sum_o wef[o] * W_out[d][o][e];  c0 = d2_b + sum_h d2_w[h] d1_b[h]
    int t = threadIdx.x;
    int d = t >> 4, e = t & 15;
    float acc = 0.f;
#pragma unroll
    for (int o = 0; o < 8; ++o) {
      float wef = 0.f;
      for (int hh = 0; hh < 24; ++hh) wef += d2_w[hh] * d1_w[hh*8 + o];
      acc += wef * W_out[d*128 + o*16 + e];
    }
    float* wf = reinterpret_cast<float*>(ws);
    wf[262144 + t] = acc;
    if (t == 0) {
      float c0 = d2_b[0];
      for (int hh = 0; hh < 24; ++hh) c0 += d2_w[hh] * d1_b[hh];
      wf[262400] = c0;
    }
  }
}

// ---------------- main: 4 waves/block {L0,L1,R0,R1}, 32 samples/wave, 256 blocks ------
__global__ __launch_bounds__(256, 1) void mps_main(
    const float* __restrict__ x, const float* __restrict__ W0,
    const float* __restrict__ WN, const unsigned short* __restrict__ ws,
    float* __restrict__ out)
{
  __shared__ __align__(16) unsigned short sbuf[2][2][CHUNKP][4][64][8]; // 64 KiB
  __shared__ float fin[2][64][16];                                      // 8 KiB

  const int tidx = threadIdx.x;
  const int wave = tidx >> 6;
  const int lane = tidx & 63;
  const int side = wave >> 1;
  const int q    = wave & 1;
  const int col  = lane & 31;
  const int h    = lane >> 5;
  const int b    = blockIdx.x * 64 + q * 32 + col;
  const float* xrow = x + (size_t)b * F_N;
  const unsigned short* frag = ws + (size_t)side * WS_SIDE_STRIDE;

  // init state in B-operand layout: lane holds v[8h+i]
  float f0[8];
  {
    float xi = side ? xrow[F_N-1] : xrow[0];
#pragma unroll
    for (int i = 0; i < 8; ++i) {
      int idx = h*8 + i;
      float a0 = side ? WN[idx*2]   : W0[idx];
      float a1 = side ? WN[idx*2+1] : W0[16+idx];
      f0[i] = fmaf(xi, a1, a0);
    }
  }
  unsigned vhi[4], vlo[4];
  split_pack8(f0, vhi, vlo);

  f32x16 Dz;
#pragma unroll
  for (int i = 0; i < 16; ++i) Dz[i] = 0.f;

  auto stage = [&](int chunk, int db) {
    const unsigned short* gs = frag + (size_t)chunk * (CHUNKP * 2048);
#pragma unroll
    for (int s2 = 0; s2 < 8; ++s2) {
      int idx = q*8 + s2;
      int pr = idx >> 2, fg = idx & 3;
      __builtin_amdgcn_global_load_lds(
        (const __attribute__((address_space(1))) void*)(gs + pr*2048 + fg*512 + lane*8),
        (__attribute__((address_space(3))) void*)(&sbuf[side][db][pr][fg][0][0]),
        16, 0, 0);
    }
  };

  auto xp0 = [&](int c) { return xrow + (side ? (504 - 8*c) : (8*c)); };
  auto xp1 = [&](int c) { return xrow + (side ? (508 - 8*c) : (8*c + 4)); };

  float4 xc0 = *reinterpret_cast<const float4*>(xp0(0));
  float4 xc1 = *reinterpret_cast<const float4*>(xp1(0));

  stage(0, 0);
  asm volatile("s_waitcnt vmcnt(0)" ::: "memory");
  __syncthreads();

  float dcomb[8];
#pragma unroll 1
  for (int c = 0; c < NCHUNKC; ++c) {
    float4 xn0 = xc0, xn1 = xc1;
    if (c + 1 < NCHUNKC) {
      stage(c + 1, (c + 1) & 1);
      xn0 = *reinterpret_cast<const float4*>(xp0(c + 1));
      xn1 = *reinterpret_cast<const float4*>(xp1(c + 1));
    }
    const unsigned short* lb = &sbuf[side][c & 1][0][0][0][0];
    s16x8 fr[16];
#pragma unroll
    for (int i = 0; i < 16; ++i)
      fr[i] = *reinterpret_cast<const s16x8*>(lb + i*512 + lane*8);

#pragma unroll
    for (int p4 = 0; p4 < 4; ++p4) {
      float xa, xbv;
      if (side == 0) {
        xa  = (p4 == 0) ? xc0.x : (p4 == 1) ? xc0.z : (p4 == 2) ? xc1.x : xc1.z;
        xbv = (p4 == 0) ? xc0.y : (p4 == 1) ? xc0.w : (p4 == 2) ? xc1.y : xc1.w;
      } else {
        xa  = (p4 == 0) ? xc1.w : (p4 == 1) ? xc1.y : (p4 == 2) ? xc0.w : xc0.y;
        xbv = (p4 == 0) ? xc1.z : (p4 == 1) ? xc1.x : (p4 == 2) ? xc0.z : xc0.x;
      }
      s16x8 vh = as_s16x8(vhi);
      s16x8 vl = as_s16x8(vlo);
      f32x16 D1 = __builtin_amdgcn_mfma_f32_32x32x16_bf16(fr[p4*4+0], vh, Dz, 0, 0, 0);
      f32x16 D2 = __builtin_amdgcn_mfma_f32_32x32x16_bf16(fr[p4*4+2], vh, Dz, 0, 0, 0);
      D1 = __builtin_amdgcn_mfma_f32_32x32x16_bf16(fr[p4*4+0], vl, D1, 0, 0, 0);
      D2 = __builtin_amdgcn_mfma_f32_32x32x16_bf16(fr[p4*4+2], vl, D2, 0, 0, 0);
      D1 = __builtin_amdgcn_mfma_f32_32x32x16_bf16(fr[p4*4+1], vh, D1, 0, 0, 0);
      D2 = __builtin_amdgcn_mfma_f32_32x32x16_bf16(fr[p4*4+3], vh, D2, 0, 0, 0);
#pragma unroll
      for (int r = 0; r < 8; ++r)
        dcomb[r] = fmaf(xbv, fmaf(xa, D2[r+8], D2[r]), fmaf(xa, D1[r+8], D1[r]));
      unsigned P[4], Q[4];
      split_pack8(dcomb, P, Q);
      half_swap32(P[0], P[2]);  half_swap32(P[1], P[3]);
      half_swap32(Q[0], Q[2]);  half_swap32(Q[1], Q[3]);
      vhi[0]=P[0]; vhi[1]=P[1]; vhi[2]=P[2]; vhi[3]=P[3];
      vlo[0]=Q[0]; vlo[1]=Q[1]; vlo[2]=Q[2]; vlo[3]=Q[3];
    }
    asm volatile("s_waitcnt vmcnt(0)" ::: "memory");
    __syncthreads();
    xc0 = xn0; xc1 = xn1;
  }

  // final f32 state (D-layout) -> LDS, then per-sample head y = c0 + v^T M u
#pragma unroll
  for (int r = 0; r < 8; ++r) {
    int row = (r & 3) + 8*(r >> 2) + 4*h;
    fin[side][q*32 + col][row] = dcomb[r];
  }
  __syncthreads();
  {
    int s = tidx >> 2, j = tidx & 3;             // 64 samples x 4 threads
    const float* Mf = reinterpret_cast<const float*>(ws) + 262144;
    float c0 = reinterpret_cast<const float*>(ws)[262400];
    float acc = 0.f;
#pragma unroll
    for (int dd = 0; dd < 4; ++dd) {
      int d = j*4 + dd;
      float zd = 0.f;
#pragma unroll
      for (int e = 0; e < 16; ++e) zd = fmaf(Mf[d*16 + e], fin[1][s][e], zd);
      acc = fmaf(fin[0][s][d], zd, acc);
    }
    acc += __shfl_xor(acc, 1, 64);
    acc += __shfl_xor(acc, 2, 64);
    if (j == 0) out[blockIdx.x*64 + s] = acc + c0;
  }
}

extern "C" void kernel_launch(void* const* d_in, const int* in_sizes, int n_in,
                              void* d_out, int out_size, void* d_ws, size_t ws_size,
                              hipStream_t stream)
{
  const float* x       = (const float*)d_in[0];
  const float* W0      = (const float*)d_in[1];
  const float* W_left  = (const float*)d_in[2];
  const float* W_out   = (const float*)d_in[3];
  const float* W_right = (const float*)d_in[4];
  const float* WN      = (const float*)d_in[5];
  const float* d1_w    = (const float*)d_in[6];
  const float* d1_b    = (const float*)d_in[7];
  const float* d2_w    = (const float*)d_in[8];
  const float* d2_b    = (const float*)d_in[9];
  unsigned short* ws   = (unsigned short*)d_ws;
  float* out           = (float*)d_out;

  if (ws_size < (size_t)WS_BYTES_NEEDED) return;

  hipLaunchKernelGGL(mps_prep, dim3(257), dim3(256), 0, stream,
                     W0, W_left, W_out, W_right, WN, d1_w, d1_b, d2_w, d2_b, ws);
  hipLaunchKernelGGL(mps_main, dim3(256), dim3(256), 0, stream,
                     x, W0, WN, ws, out);
}